// Round 4
// baseline (509.238 us; speedup 1.0000x reference)
//
#include <hip/hip_runtime.h>
#include <math.h>

#define N_NODES 8192
#define NFEAT 256
#define NHID 64
#define NHEADS 4
#define NCLASS 121
#define NCPAD 128
#define CAP 256
#define LRALPHA 0.2f

typedef float f32x4 __attribute__((ext_vector_type(4)));
typedef float f32x2 __attribute__((ext_vector_type(2)));

__device__ __forceinline__ float lrelu(float x) { return x > 0.f ? x : LRALPHA * x; }
__device__ __forceinline__ f32x4 splat4(float v) { f32x4 r = {v, v, v, v}; return r; }

// ---------------------------------------------------------------------------
// K1: build per-row neighbor lists from dense adjacency (one block per row).
// adj is 0.0/1.0 float; ~82 edges/row expected, CAP=256 is ~19 sigma headroom.
// Nontemporal: adj is read-once 256 MB, keep it out of L2.
// ---------------------------------------------------------------------------
__global__ __launch_bounds__(256) void build_csr(const float* __restrict__ adj,
                                                 int* __restrict__ nbr,
                                                 int* __restrict__ deg) {
    int row = blockIdx.x;
    __shared__ int cnt;
    if (threadIdx.x == 0) cnt = 0;
    __syncthreads();
    const f32x4* arow = (const f32x4*)(adj + (size_t)row * N_NODES);
    for (int j4 = threadIdx.x; j4 < N_NODES / 4; j4 += 256) {
        f32x4 v = __builtin_nontemporal_load(&arow[j4]);
        if (v.x > 0.f) { int s = atomicAdd(&cnt, 1); if (s < CAP) nbr[row * CAP + s] = j4 * 4 + 0; }
        if (v.y > 0.f) { int s = atomicAdd(&cnt, 1); if (s < CAP) nbr[row * CAP + s] = j4 * 4 + 1; }
        if (v.z > 0.f) { int s = atomicAdd(&cnt, 1); if (s < CAP) nbr[row * CAP + s] = j4 * 4 + 2; }
        if (v.w > 0.f) { int s = atomicAdd(&cnt, 1); if (s < CAP) nbr[row * CAP + s] = j4 * 4 + 3; }
    }
    __syncthreads();
    if (threadIdx.x == 0) deg[row] = cnt < CAP ? cnt : CAP;
}

// ---------------------------------------------------------------------------
// K2: pad W_out [256,121] -> [256,128] (zeros) and a_out [242] -> [256].
// ---------------------------------------------------------------------------
__global__ __launch_bounds__(256) void pad_params(const float* __restrict__ Wout,
                                                  const float* __restrict__ aout,
                                                  float* __restrict__ Wpad,
                                                  float* __restrict__ apad) {
    int idx = blockIdx.x * 256 + threadIdx.x;
    if (idx < 256 * NCPAD) {
        int k = idx >> 7, c = idx & 127;
        Wpad[idx] = (c < NCLASS) ? Wout[k * NCLASS + c] : 0.f;
    }
    if (idx < 256) {
        int c = idx & 127;
        float v = 0.f;
        if (c < NCLASS) v = (idx < 128) ? aout[c] : aout[NCLASS + c];
        apad[idx] = v;
    }
}

// ---------------------------------------------------------------------------
// K3: layer-1 GEMM + fused attention-coefficient epilogue.
// Output INTERLEAVED Wh1[i][h*64+d], stored NONTEMPORAL so the aggregation's
// cross-XCD gathers hit clean LLC lines instead of probing dirty L2s.
// fs1t/fd1t computed in-wave (wave = 16 rows x 64 dims of one head).
// ---------------------------------------------------------------------------
__global__ __launch_bounds__(256) void gemm1(const float* __restrict__ x,
                                             const float* __restrict__ Ws,
                                             const float* __restrict__ a_heads,
                                             float* __restrict__ Wh1,
                                             float* __restrict__ fs1t,
                                             float* __restrict__ fd1t) {
    int h = blockIdx.y;
    int r0 = blockIdx.x * 64;
    __shared__ float xs[64][260];
    for (int t = threadIdx.x; t < 64 * 64; t += 256) {
        int r = t >> 6, c4 = t & 63;
        *(float4*)&xs[r][c4 * 4] = *(const float4*)(x + (size_t)(r0 + r) * NFEAT + c4 * 4);
    }
    __syncthreads();
    int d = threadIdx.x & 63;
    int rb = (threadIdx.x >> 6) * 16;
    const float* W = Ws + (size_t)h * NFEAT * NHID + d;  // W[k][d]
    float acc[16] = {};
    for (int k4 = 0; k4 < NFEAT; k4 += 4) {
        float b0 = W[(k4 + 0) * NHID];
        float b1 = W[(k4 + 1) * NHID];
        float b2 = W[(k4 + 2) * NHID];
        float b3 = W[(k4 + 3) * NHID];
#pragma unroll
        for (int r = 0; r < 16; r++) {
            float4 a = *(const float4*)&xs[rb + r][k4];
            acc[r] += a.x * b0 + a.y * b1 + a.z * b2 + a.w * b3;
        }
    }
    float ah_s = a_heads[h * 2 * NHID + d];
    float ah_d = a_heads[h * 2 * NHID + NHID + d];
#pragma unroll
    for (int r = 0; r < 16; r++) {
        __builtin_nontemporal_store(acc[r],
            &Wh1[(size_t)(r0 + rb + r) * (NHEADS * NHID) + h * NHID + d]);
        float s = acc[r] * ah_s;
        float dd = acc[r] * ah_d;
#pragma unroll
        for (int o = 32; o > 0; o >>= 1) { s += __shfl_xor(s, o); dd += __shfl_xor(dd, o); }
        if (d == 0) {
            __builtin_nontemporal_store(s, &fs1t[(size_t)(r0 + rb + r) * 4 + h]);
            __builtin_nontemporal_store(dd, &fd1t[(size_t)(r0 + rb + r) * 4 + h]);
        }
    }
}

// ---------------------------------------------------------------------------
// K5: layer-1 sparse softmax (4 heads packed) + aggregate + ELU.
// ONE WAVE PER NODE: per edge, a single global_load_dwordx4 fetches the full
// 1 KB row Wh1[j][0:256] (lane l -> head l>>4, dims 4l..4l+3), serving all
// 4 heads at once. Softmax computed packed float4 in registers.
// ---------------------------------------------------------------------------
__global__ __launch_bounds__(256) void attn_agg1(const int* __restrict__ nbr,
                                                 const int* __restrict__ deg,
                                                 const float* __restrict__ Wh1,
                                                 const float* __restrict__ fs1t,
                                                 const float* __restrict__ fd1t,
                                                 float* __restrict__ hcat) {
    int w = threadIdx.x >> 6, lane = threadIdx.x & 63;
    int i = blockIdx.x * 4 + w;
    __shared__ int nbrs[4][CAP];
    __shared__ float pbuf[4][CAP][4];   // per-edge per-head softmax numerators
    int dg = deg[i];
    for (int t = lane; t < dg; t += 64)
        nbrs[w][t] = nbr[i * CAP + t];
    f32x4 fsi = *(const f32x4*)(fs1t + (size_t)i * 4);
    f32x4 e[4];
    f32x4 m4 = {-3.4e38f, -3.4e38f, -3.4e38f, -3.4e38f};
#pragma unroll
    for (int k = 0; k < 4; k++) {
        int t = lane + (k << 6);
        if (t < dg) {
            int j = nbrs[w][t];                         // own lane's writes
            f32x4 fdj = *(const f32x4*)(fd1t + (size_t)j * 4);
            f32x4 ev;
            ev.x = lrelu(fsi.x + fdj.x);
            ev.y = lrelu(fsi.y + fdj.y);
            ev.z = lrelu(fsi.z + fdj.z);
            ev.w = lrelu(fsi.w + fdj.w);
            e[k] = ev;
            m4.x = fmaxf(m4.x, ev.x); m4.y = fmaxf(m4.y, ev.y);
            m4.z = fmaxf(m4.z, ev.z); m4.w = fmaxf(m4.w, ev.w);
        }
    }
#pragma unroll
    for (int o = 32; o > 0; o >>= 1) {
        m4.x = fmaxf(m4.x, __shfl_xor(m4.x, o));
        m4.y = fmaxf(m4.y, __shfl_xor(m4.y, o));
        m4.z = fmaxf(m4.z, __shfl_xor(m4.z, o));
        m4.w = fmaxf(m4.w, __shfl_xor(m4.w, o));
    }
    f32x4 s4 = {0.f, 0.f, 0.f, 0.f};
#pragma unroll
    for (int k = 0; k < 4; k++) {
        int t = lane + (k << 6);
        if (t < dg) {
            f32x4 p;
            p.x = __expf(e[k].x - m4.x);
            p.y = __expf(e[k].y - m4.y);
            p.z = __expf(e[k].z - m4.z);
            p.w = __expf(e[k].w - m4.w);
            *(f32x4*)&pbuf[w][t][0] = p;
            s4 += p;
        }
    }
#pragma unroll
    for (int o = 32; o > 0; o >>= 1) {
        s4.x += __shfl_xor(s4.x, o);
        s4.y += __shfl_xor(s4.y, o);
        s4.z += __shfl_xor(s4.z, o);
        s4.w += __shfl_xor(s4.w, o);
    }
    __syncthreads();  // nbrs + pbuf cross-lane visibility
    int hl = lane >> 4;
    const float* wrow = Wh1 + 4 * lane;
    f32x4 acc = {0.f, 0.f, 0.f, 0.f};
#pragma unroll 8
    for (int t = 0; t < dg; t++) {
        int j = nbrs[w][t];
        float p = pbuf[w][t][hl];
        f32x4 wv = *(const f32x4*)(wrow + (size_t)j * (NHEADS * NHID));
        acc += wv * splat4(p);
    }
    float sh = hl == 0 ? s4.x : hl == 1 ? s4.y : hl == 2 ? s4.z : s4.w;
    acc.x /= sh; acc.y /= sh; acc.z /= sh; acc.w /= sh;
    acc.x = acc.x > 0.f ? acc.x : expm1f(acc.x);
    acc.y = acc.y > 0.f ? acc.y : expm1f(acc.y);
    acc.z = acc.z > 0.f ? acc.z : expm1f(acc.z);
    acc.w = acc.w > 0.f ? acc.w : expm1f(acc.w);
    f32x4 r = acc;
    __builtin_nontemporal_store(r, (f32x4*)(hcat + (size_t)i * (NHEADS * NHID) + 4 * lane));
}

// ---------------------------------------------------------------------------
// K6: layer-2 GEMM + fused coefficient epilogue. Row-major Wh2[i][128],
// nontemporal stores (gathered next by attn_agg2 from all XCDs).
// ---------------------------------------------------------------------------
__global__ __launch_bounds__(256) void gemm2(const float* __restrict__ hcat,
                                             const float* __restrict__ Wpad,
                                             const float* __restrict__ apad,
                                             float* __restrict__ Wh2,
                                             float* __restrict__ fs2,
                                             float* __restrict__ fd2) {
    int r0 = blockIdx.x * 64;
    __shared__ float xs[64][260];
    for (int t = threadIdx.x; t < 64 * 64; t += 256) {
        int r = t >> 6, c4 = t & 63;
        *(float4*)&xs[r][c4 * 4] = *(const float4*)(hcat + (size_t)(r0 + r) * 256 + c4 * 4);
    }
    __syncthreads();
    int c0 = (threadIdx.x & 63) * 2;
    int rb = (threadIdx.x >> 6) * 16;
    float acc0[16] = {}, acc1[16] = {};
    for (int k4 = 0; k4 < 256; k4 += 4) {
        float2 b0 = *(const float2*)&Wpad[(k4 + 0) * NCPAD + c0];
        float2 b1 = *(const float2*)&Wpad[(k4 + 1) * NCPAD + c0];
        float2 b2 = *(const float2*)&Wpad[(k4 + 2) * NCPAD + c0];
        float2 b3 = *(const float2*)&Wpad[(k4 + 3) * NCPAD + c0];
#pragma unroll
        for (int r = 0; r < 16; r++) {
            float4 a = *(const float4*)&xs[rb + r][k4];
            acc0[r] += a.x * b0.x + a.y * b1.x + a.z * b2.x + a.w * b3.x;
            acc1[r] += a.x * b0.y + a.y * b1.y + a.z * b2.y + a.w * b3.y;
        }
    }
    float as0 = apad[c0], as1 = apad[c0 + 1];
    float ad0 = apad[128 + c0], ad1 = apad[128 + c0 + 1];
#pragma unroll
    for (int r = 0; r < 16; r++) {
        f32x2 v = {acc0[r], acc1[r]};
        __builtin_nontemporal_store(v, (f32x2*)&Wh2[(size_t)(r0 + rb + r) * NCPAD + c0]);
        float s = acc0[r] * as0 + acc1[r] * as1;
        float dd = acc0[r] * ad0 + acc1[r] * ad1;
#pragma unroll
        for (int o = 32; o > 0; o >>= 1) { s += __shfl_xor(s, o); dd += __shfl_xor(dd, o); }
        if ((threadIdx.x & 63) == 0) {
            __builtin_nontemporal_store(s, &fs2[r0 + rb + r]);
            __builtin_nontemporal_store(dd, &fd2[r0 + rb + r]);
        }
    }
}

// ---------------------------------------------------------------------------
// K8: layer-2 sparse softmax + aggregate. ONE WAVE PER NODE; gather processes
// 2 edges/iteration (lane half eg=l>>5 takes edge t+eg, float4 over 128 cols),
// halves combined by shfl_xor(32) at the end.
// ---------------------------------------------------------------------------
__global__ __launch_bounds__(256) void attn_agg2(const int* __restrict__ nbr,
                                                 const int* __restrict__ deg,
                                                 const float* __restrict__ Wh2,
                                                 const float* __restrict__ fs2,
                                                 const float* __restrict__ fd2,
                                                 float* __restrict__ out) {
    int w = threadIdx.x >> 6, lane = threadIdx.x & 63;
    int i = blockIdx.x * 4 + w;
    __shared__ int nbrs[4][CAP];
    __shared__ float pbuf[4][CAP];
    int dg = deg[i];
    for (int t = lane; t < dg; t += 64)
        nbrs[w][t] = nbr[i * CAP + t];
    float fsi = fs2[i];
    float e[4];
    float m = -3.4e38f;
#pragma unroll
    for (int k = 0; k < 4; k++) {
        int t = lane + (k << 6);
        if (t < dg) {
            float ev = lrelu(fsi + fd2[nbrs[w][t]]);
            e[k] = ev;
            m = fmaxf(m, ev);
        }
    }
#pragma unroll
    for (int o = 32; o > 0; o >>= 1) m = fmaxf(m, __shfl_xor(m, o));
    float s = 0.f;
#pragma unroll
    for (int k = 0; k < 4; k++) {
        int t = lane + (k << 6);
        if (t < dg) {
            float p = __expf(e[k] - m);
            pbuf[w][t] = p;
            s += p;
        }
    }
#pragma unroll
    for (int o = 32; o > 0; o >>= 1) s += __shfl_xor(s, o);
    __syncthreads();  // nbrs + pbuf cross-lane visibility
    int eg = lane >> 5, c = lane & 31;
    const float* wrow = Wh2 + 4 * c;
    f32x4 acc = {0.f, 0.f, 0.f, 0.f};
#pragma unroll 4
    for (int tt = 0; tt < dg; tt += 2) {
        int t = tt + eg;
        int tc = t < dg ? t : 0;         // dg >= 1 (self-loop)
        float p = t < dg ? pbuf[w][tc] : 0.f;
        int j = nbrs[w][tc];
        f32x4 wv = *(const f32x4*)(wrow + (size_t)j * NCPAD);
        acc += wv * splat4(p);
    }
    acc.x += __shfl_xor(acc.x, 32);
    acc.y += __shfl_xor(acc.y, 32);
    acc.z += __shfl_xor(acc.z, 32);
    acc.w += __shfl_xor(acc.w, 32);
    if (eg == 0) {
        int c4 = c * 4;
#pragma unroll
        for (int q = 0; q < 4; q++)
            if (c4 + q < NCLASS)
                __builtin_nontemporal_store(acc[q] / s, &out[(size_t)i * NCLASS + c4 + q]);
    }
}

// ---------------------------------------------------------------------------

extern "C" void kernel_launch(void* const* d_in, const int* in_sizes, int n_in,
                              void* d_out, int out_size, void* d_ws, size_t ws_size,
                              hipStream_t stream) {
    const float* x       = (const float*)d_in[0];  // [8192,256]
    const float* adj     = (const float*)d_in[1];  // [8192,8192]
    const float* Ws      = (const float*)d_in[2];  // [4,256,64]
    const float* a_heads = (const float*)d_in[3];  // [4,128]
    const float* Wout    = (const float*)d_in[4];  // [256,121]
    const float* aout    = (const float*)d_in[5];  // [242]
    float* out = (float*)d_out;                    // [8192,121]

    char* ws = (char*)d_ws;
    size_t off = 0;
    auto alloc = [&](size_t bytes) { void* p = ws + off; off = (off + bytes + 255) & ~(size_t)255; return p; };
    int*   nbr  = (int*)  alloc((size_t)N_NODES * CAP * 4);            // 8 MB
    int*   deg  = (int*)  alloc((size_t)N_NODES * 4);                  // 32 KB
    float* Wh1  = (float*)alloc((size_t)N_NODES * NHEADS * NHID * 4);  // 8 MB, interleaved rows
    float* fs1t = (float*)alloc((size_t)N_NODES * 4 * 4);              // 128 KB, node-major float4
    float* fd1t = (float*)alloc((size_t)N_NODES * 4 * 4);              // 128 KB
    float* hcat = (float*)alloc((size_t)N_NODES * NHEADS * NHID * 4);  // 8 MB
    float* Wh2  = (float*)alloc((size_t)N_NODES * NCPAD * 4);          // 4 MB
    float* fs2  = (float*)alloc((size_t)N_NODES * 4);
    float* fd2  = (float*)alloc((size_t)N_NODES * 4);
    float* Wpad = (float*)alloc((size_t)256 * NCPAD * 4);
    float* apad = (float*)alloc((size_t)256 * 4);

    build_csr<<<N_NODES, 256, 0, stream>>>(adj, nbr, deg);
    pad_params<<<128, 256, 0, stream>>>(Wout, aout, Wpad, apad);
    gemm1<<<dim3(N_NODES / 64, NHEADS), 256, 0, stream>>>(x, Ws, a_heads, Wh1, fs1t, fd1t);
    attn_agg1<<<N_NODES / 4, 256, 0, stream>>>(nbr, deg, Wh1, fs1t, fd1t, hcat);
    gemm2<<<N_NODES / 64, 256, 0, stream>>>(hcat, Wpad, apad, Wh2, fs2, fd2);
    attn_agg2<<<N_NODES / 4, 256, 0, stream>>>(nbr, deg, Wh2, fs2, fd2, out);
}

// Round 5
// 498.279 us; speedup vs baseline: 1.0220x; 1.0220x over previous
//
#include <hip/hip_runtime.h>
#include <math.h>

#define N_NODES 8192
#define NFEAT 256
#define NHID 64
#define NHEADS 4
#define NCLASS 121
#define NCPAD 128
#define CAP 256
#define LRALPHA 0.2f

typedef float f32x4 __attribute__((ext_vector_type(4)));

__device__ __forceinline__ float lrelu(float x) { return x > 0.f ? x : LRALPHA * x; }
__device__ __forceinline__ f32x4 splat4(float v) { f32x4 r = {v, v, v, v}; return r; }

// ---------------------------------------------------------------------------
// K1: build per-row neighbor lists from dense adjacency (one block per row).
// ---------------------------------------------------------------------------
__global__ __launch_bounds__(256) void build_csr(const float* __restrict__ adj,
                                                 int* __restrict__ nbr,
                                                 int* __restrict__ deg) {
    int row = blockIdx.x;
    __shared__ int cnt;
    if (threadIdx.x == 0) cnt = 0;
    __syncthreads();
    const f32x4* arow = (const f32x4*)(adj + (size_t)row * N_NODES);
    for (int j4 = threadIdx.x; j4 < N_NODES / 4; j4 += 256) {
        f32x4 v = __builtin_nontemporal_load(&arow[j4]);
        if (v.x > 0.f) { int s = atomicAdd(&cnt, 1); if (s < CAP) nbr[row * CAP + s] = j4 * 4 + 0; }
        if (v.y > 0.f) { int s = atomicAdd(&cnt, 1); if (s < CAP) nbr[row * CAP + s] = j4 * 4 + 1; }
        if (v.z > 0.f) { int s = atomicAdd(&cnt, 1); if (s < CAP) nbr[row * CAP + s] = j4 * 4 + 2; }
        if (v.w > 0.f) { int s = atomicAdd(&cnt, 1); if (s < CAP) nbr[row * CAP + s] = j4 * 4 + 3; }
    }
    __syncthreads();
    if (threadIdx.x == 0) deg[row] = cnt < CAP ? cnt : CAP;
}

// ---------------------------------------------------------------------------
// K2: pad W_out [256,121] -> [256,128] (zeros) and a_out [242] -> [256].
// ---------------------------------------------------------------------------
__global__ __launch_bounds__(256) void pad_params(const float* __restrict__ Wout,
                                                  const float* __restrict__ aout,
                                                  float* __restrict__ Wpad,
                                                  float* __restrict__ apad) {
    int idx = blockIdx.x * 256 + threadIdx.x;
    if (idx < 256 * NCPAD) {
        int k = idx >> 7, c = idx & 127;
        Wpad[idx] = (c < NCLASS) ? Wout[k * NCLASS + c] : 0.f;
    }
    if (idx < 256) {
        int c = idx & 127;
        float v = 0.f;
        if (c < NCLASS) v = (idx < 128) ? aout[c] : aout[NCLASS + c];
        apad[idx] = v;
    }
}

// ---------------------------------------------------------------------------
// K3: layer-1 GEMM. Output INTERLEAVED: Wh1[i][h*64+d] (full 1 KB node rows).
// Plain stores (data must stay cached — NT here regressed, round 4).
// ---------------------------------------------------------------------------
__global__ __launch_bounds__(256) void gemm1(const float* __restrict__ x,
                                             const float* __restrict__ Ws,
                                             float* __restrict__ Wh1) {
    int h = blockIdx.y;
    int r0 = blockIdx.x * 64;
    __shared__ float xs[64][260];
    for (int t = threadIdx.x; t < 64 * 64; t += 256) {
        int r = t >> 6, c4 = t & 63;
        *(float4*)&xs[r][c4 * 4] = *(const float4*)(x + (size_t)(r0 + r) * NFEAT + c4 * 4);
    }
    __syncthreads();
    int d = threadIdx.x & 63;
    int rb = (threadIdx.x >> 6) * 16;
    const float* W = Ws + (size_t)h * NFEAT * NHID + d;  // W[k][d]
    float acc[16] = {};
    for (int k4 = 0; k4 < NFEAT; k4 += 4) {
        float b0 = W[(k4 + 0) * NHID];
        float b1 = W[(k4 + 1) * NHID];
        float b2 = W[(k4 + 2) * NHID];
        float b3 = W[(k4 + 3) * NHID];
#pragma unroll
        for (int r = 0; r < 16; r++) {
            float4 a = *(const float4*)&xs[rb + r][k4];
            acc[r] += a.x * b0 + a.y * b1 + a.z * b2 + a.w * b3;
        }
    }
#pragma unroll
    for (int r = 0; r < 16; r++)
        Wh1[(size_t)(r0 + rb + r) * (NHEADS * NHID) + h * NHID + d] = acc[r];
}

// ---------------------------------------------------------------------------
// K4: layer-1 attention coefficients. Block = node, wave = head.
// Outputs NODE-MAJOR float4: fs1t[i][h], fd1t[i][h].
// ---------------------------------------------------------------------------
__global__ __launch_bounds__(256) void attn_coef1(const float* __restrict__ Wh1,
                                                  const float* __restrict__ a_heads,
                                                  float* __restrict__ fs1t,
                                                  float* __restrict__ fd1t) {
    int i = blockIdx.x;
    int h = threadIdx.x >> 6, lane = threadIdx.x & 63;
    float wh = Wh1[(size_t)i * (NHEADS * NHID) + h * NHID + lane];
    float s = wh * a_heads[h * 2 * NHID + lane];
    float dd = wh * a_heads[h * 2 * NHID + NHID + lane];
#pragma unroll
    for (int o = 32; o > 0; o >>= 1) { s += __shfl_down(s, o); dd += __shfl_down(dd, o); }
    if (lane == 0) { fs1t[i * 4 + h] = s; fd1t[i * 4 + h] = dd; }
}

// ---------------------------------------------------------------------------
// K5: layer-1 sparse softmax (4 heads packed) + aggregate + ELU.
// ONE WAVE PER NODE, full 1 KB row per edge (all 4 heads at once).
// NEW: edges counting-sorted by source CHUNK (8 x 1024-node = 1 MB slices of
// Wh1); all co-resident blocks walk chunks in the same order, so the gather
// working set at any instant is ~1-3 MB -> local-L2-resident in every XCD
// instead of random cross-XCD service over the full 8 MB.
// ---------------------------------------------------------------------------
__global__ __launch_bounds__(256) void attn_agg1(const int* __restrict__ nbr,
                                                 const int* __restrict__ deg,
                                                 const float* __restrict__ Wh1,
                                                 const float* __restrict__ fs1t,
                                                 const float* __restrict__ fd1t,
                                                 float* __restrict__ hcat) {
    int w = threadIdx.x >> 6, lane = threadIdx.x & 63;
    int i = blockIdx.x * 4 + w;
    __shared__ int nbrs[4][CAP];
    __shared__ float pbuf[4][CAP][4];        // per-edge per-head softmax numerators
    __shared__ unsigned short sorted[4][CAP];
    __shared__ int bkt[4][8];
    int dg = deg[i];
    for (int t = lane; t < dg; t += 64)
        nbrs[w][t] = nbr[i * CAP + t];
    f32x4 fsi = *(const f32x4*)(fs1t + (size_t)i * 4);
    f32x4 e[4];
    f32x4 m4 = splat4(-3.4e38f);
#pragma unroll
    for (int k = 0; k < 4; k++) {
        int t = lane + (k << 6);
        if (t < dg) {
            int j = nbrs[w][t];                         // own lane's writes
            f32x4 fdj = *(const f32x4*)(fd1t + (size_t)j * 4);
            f32x4 ev;
            ev.x = lrelu(fsi.x + fdj.x);
            ev.y = lrelu(fsi.y + fdj.y);
            ev.z = lrelu(fsi.z + fdj.z);
            ev.w = lrelu(fsi.w + fdj.w);
            e[k] = ev;
            m4.x = fmaxf(m4.x, ev.x); m4.y = fmaxf(m4.y, ev.y);
            m4.z = fmaxf(m4.z, ev.z); m4.w = fmaxf(m4.w, ev.w);
        }
    }
#pragma unroll
    for (int o = 32; o > 0; o >>= 1) {
        m4.x = fmaxf(m4.x, __shfl_xor(m4.x, o));
        m4.y = fmaxf(m4.y, __shfl_xor(m4.y, o));
        m4.z = fmaxf(m4.z, __shfl_xor(m4.z, o));
        m4.w = fmaxf(m4.w, __shfl_xor(m4.w, o));
    }
    f32x4 s4 = splat4(0.f);
#pragma unroll
    for (int k = 0; k < 4; k++) {
        int t = lane + (k << 6);
        if (t < dg) {
            f32x4 p;
            p.x = __expf(e[k].x - m4.x);
            p.y = __expf(e[k].y - m4.y);
            p.z = __expf(e[k].z - m4.z);
            p.w = __expf(e[k].w - m4.w);
            *(f32x4*)&pbuf[w][t][0] = p;
            s4 += p;
        }
    }
#pragma unroll
    for (int o = 32; o > 0; o >>= 1) {
        s4.x += __shfl_xor(s4.x, o);
        s4.y += __shfl_xor(s4.y, o);
        s4.z += __shfl_xor(s4.z, o);
        s4.w += __shfl_xor(s4.w, o);
    }
    if (lane < 8) bkt[w][lane] = 0;
    __syncthreads();          // nbrs/pbuf visibility + bkt zeroed
    // --- counting sort of edge indices by source chunk (j>>10) ---
    for (int t = lane; t < dg; t += 64)
        atomicAdd(&bkt[w][nbrs[w][t] >> 10], 1);
    __syncthreads();
    if (lane == 0) {
        int run = 0;
#pragma unroll
        for (int c = 0; c < 8; c++) { int v = bkt[w][c]; bkt[w][c] = run; run += v; }
    }
    __syncthreads();
    for (int t = lane; t < dg; t += 64) {
        int pos = atomicAdd(&bkt[w][nbrs[w][t] >> 10], 1);
        sorted[w][pos] = (unsigned short)t;
    }
    __syncthreads();
    // --- chunk-ordered gather ---
    int hl = lane >> 4;
    const float* wrow = Wh1 + 4 * lane;
    f32x4 acc = splat4(0.f);
#pragma unroll 8
    for (int t = 0; t < dg; t++) {
        int tt = sorted[w][t];
        int j = nbrs[w][tt];
        float p = pbuf[w][tt][hl];
        f32x4 wv = *(const f32x4*)(wrow + (size_t)j * (NHEADS * NHID));
        acc += wv * splat4(p);
    }
    float sh = hl == 0 ? s4.x : hl == 1 ? s4.y : hl == 2 ? s4.z : s4.w;
    acc.x /= sh; acc.y /= sh; acc.z /= sh; acc.w /= sh;
    acc.x = acc.x > 0.f ? acc.x : expm1f(acc.x);
    acc.y = acc.y > 0.f ? acc.y : expm1f(acc.y);
    acc.z = acc.z > 0.f ? acc.z : expm1f(acc.z);
    acc.w = acc.w > 0.f ? acc.w : expm1f(acc.w);
    *(f32x4*)(hcat + (size_t)i * (NHEADS * NHID) + 4 * lane) = acc;
}

// ---------------------------------------------------------------------------
// K6: layer-2 GEMM. Row-major Wh2[i][128] (full 512 B node rows).
// ---------------------------------------------------------------------------
__global__ __launch_bounds__(256) void gemm2(const float* __restrict__ hcat,
                                             const float* __restrict__ Wpad,
                                             float* __restrict__ Wh2) {
    int r0 = blockIdx.x * 64;
    __shared__ float xs[64][260];
    for (int t = threadIdx.x; t < 64 * 64; t += 256) {
        int r = t >> 6, c4 = t & 63;
        *(float4*)&xs[r][c4 * 4] = *(const float4*)(hcat + (size_t)(r0 + r) * 256 + c4 * 4);
    }
    __syncthreads();
    int c0 = (threadIdx.x & 63) * 2;
    int rb = (threadIdx.x >> 6) * 16;
    float acc0[16] = {}, acc1[16] = {};
    for (int k4 = 0; k4 < 256; k4 += 4) {
        float2 b0 = *(const float2*)&Wpad[(k4 + 0) * NCPAD + c0];
        float2 b1 = *(const float2*)&Wpad[(k4 + 1) * NCPAD + c0];
        float2 b2 = *(const float2*)&Wpad[(k4 + 2) * NCPAD + c0];
        float2 b3 = *(const float2*)&Wpad[(k4 + 3) * NCPAD + c0];
#pragma unroll
        for (int r = 0; r < 16; r++) {
            float4 a = *(const float4*)&xs[rb + r][k4];
            acc0[r] += a.x * b0.x + a.y * b1.x + a.z * b2.x + a.w * b3.x;
            acc1[r] += a.x * b0.y + a.y * b1.y + a.z * b2.y + a.w * b3.y;
        }
    }
#pragma unroll
    for (int r = 0; r < 16; r++) {
        float2 v = make_float2(acc0[r], acc1[r]);
        *(float2*)&Wh2[(size_t)(r0 + rb + r) * NCPAD + c0] = v;
    }
}

// ---------------------------------------------------------------------------
// K7: layer-2 attention coefficients. Wave per node (4 nodes/block).
// ---------------------------------------------------------------------------
__global__ __launch_bounds__(256) void attn_coef2(const float* __restrict__ Wh2,
                                                  const float* __restrict__ apad,
                                                  float* __restrict__ fs2,
                                                  float* __restrict__ fd2) {
    int i = blockIdx.x * 4 + (threadIdx.x >> 6);
    int lane = threadIdx.x & 63;
    float w0 = Wh2[(size_t)i * NCPAD + lane];
    float w1 = Wh2[(size_t)i * NCPAD + 64 + lane];
    float s = w0 * apad[lane] + w1 * apad[64 + lane];
    float dd = w0 * apad[128 + lane] + w1 * apad[192 + lane];
#pragma unroll
    for (int o = 32; o > 0; o >>= 1) { s += __shfl_down(s, o); dd += __shfl_down(dd, o); }
    if (lane == 0) { fs2[i] = s; fd2[i] = dd; }
}

// ---------------------------------------------------------------------------
// K8: layer-2 sparse softmax + aggregate. ONE WAVE PER NODE; 2 edges/iter.
// NEW: same counting-sort chunking (4 x 2048-node = 1 MB slices of Wh2).
// ---------------------------------------------------------------------------
__global__ __launch_bounds__(256) void attn_agg2(const int* __restrict__ nbr,
                                                 const int* __restrict__ deg,
                                                 const float* __restrict__ Wh2,
                                                 const float* __restrict__ fs2,
                                                 const float* __restrict__ fd2,
                                                 float* __restrict__ out) {
    int w = threadIdx.x >> 6, lane = threadIdx.x & 63;
    int i = blockIdx.x * 4 + w;
    __shared__ int nbrs[4][CAP];
    __shared__ float pbuf[4][CAP];
    __shared__ unsigned short sorted[4][CAP];
    __shared__ int bkt[4][4];
    int dg = deg[i];
    for (int t = lane; t < dg; t += 64)
        nbrs[w][t] = nbr[i * CAP + t];
    float fsi = fs2[i];
    float e[4];
    float m = -3.4e38f;
#pragma unroll
    for (int k = 0; k < 4; k++) {
        int t = lane + (k << 6);
        if (t < dg) {
            float ev = lrelu(fsi + fd2[nbrs[w][t]]);
            e[k] = ev;
            m = fmaxf(m, ev);
        }
    }
#pragma unroll
    for (int o = 32; o > 0; o >>= 1) m = fmaxf(m, __shfl_xor(m, o));
    float s = 0.f;
#pragma unroll
    for (int k = 0; k < 4; k++) {
        int t = lane + (k << 6);
        if (t < dg) {
            float p = __expf(e[k] - m);
            pbuf[w][t] = p;
            s += p;
        }
    }
#pragma unroll
    for (int o = 32; o > 0; o >>= 1) s += __shfl_xor(s, o);
    if (lane < 4) bkt[w][lane] = 0;
    __syncthreads();          // nbrs/pbuf visibility + bkt zeroed
    for (int t = lane; t < dg; t += 64)
        atomicAdd(&bkt[w][nbrs[w][t] >> 11], 1);
    __syncthreads();
    if (lane == 0) {
        int run = 0;
#pragma unroll
        for (int c = 0; c < 4; c++) { int v = bkt[w][c]; bkt[w][c] = run; run += v; }
    }
    __syncthreads();
    for (int t = lane; t < dg; t += 64) {
        int pos = atomicAdd(&bkt[w][nbrs[w][t] >> 11], 1);
        sorted[w][pos] = (unsigned short)t;
    }
    __syncthreads();
    int eg = lane >> 5, c = lane & 31;
    const float* wrow = Wh2 + 4 * c;
    f32x4 acc = splat4(0.f);
#pragma unroll 4
    for (int tt = 0; tt < dg; tt += 2) {
        int t = tt + eg;
        int tq = t < dg ? t : dg - 1;      // dg >= 1 (self-loop)
        int ts = sorted[w][tq];
        float p = t < dg ? pbuf[w][ts] : 0.f;
        int j = nbrs[w][ts];
        f32x4 wv = *(const f32x4*)(wrow + (size_t)j * NCPAD);
        acc += wv * splat4(p);
    }
    acc.x += __shfl_xor(acc.x, 32);
    acc.y += __shfl_xor(acc.y, 32);
    acc.z += __shfl_xor(acc.z, 32);
    acc.w += __shfl_xor(acc.w, 32);
    if (eg == 0) {
        int c4 = c * 4;
#pragma unroll
        for (int q = 0; q < 4; q++)
            if (c4 + q < NCLASS) out[(size_t)i * NCLASS + c4 + q] = acc[q] / s;
    }
}

// ---------------------------------------------------------------------------

extern "C" void kernel_launch(void* const* d_in, const int* in_sizes, int n_in,
                              void* d_out, int out_size, void* d_ws, size_t ws_size,
                              hipStream_t stream) {
    const float* x       = (const float*)d_in[0];  // [8192,256]
    const float* adj     = (const float*)d_in[1];  // [8192,8192]
    const float* Ws      = (const float*)d_in[2];  // [4,256,64]
    const float* a_heads = (const float*)d_in[3];  // [4,128]
    const float* Wout    = (const float*)d_in[4];  // [256,121]
    const float* aout    = (const float*)d_in[5];  // [242]
    float* out = (float*)d_out;                    // [8192,121]

    char* ws = (char*)d_ws;
    size_t off = 0;
    auto alloc = [&](size_t bytes) { void* p = ws + off; off = (off + bytes + 255) & ~(size_t)255; return p; };
    int*   nbr  = (int*)  alloc((size_t)N_NODES * CAP * 4);            // 8 MB
    int*   deg  = (int*)  alloc((size_t)N_NODES * 4);                  // 32 KB
    float* Wh1  = (float*)alloc((size_t)N_NODES * NHEADS * NHID * 4);  // 8 MB, interleaved rows
    float* fs1t = (float*)alloc((size_t)N_NODES * 4 * 4);              // 128 KB, node-major float4
    float* fd1t = (float*)alloc((size_t)N_NODES * 4 * 4);              // 128 KB
    float* hcat = (float*)alloc((size_t)N_NODES * NHEADS * NHID * 4);  // 8 MB
    float* Wh2  = (float*)alloc((size_t)N_NODES * NCPAD * 4);          // 4 MB
    float* fs2  = (float*)alloc((size_t)N_NODES * 4);
    float* fd2  = (float*)alloc((size_t)N_NODES * 4);
    float* Wpad = (float*)alloc((size_t)256 * NCPAD * 4);
    float* apad = (float*)alloc((size_t)256 * 4);

    build_csr<<<N_NODES, 256, 0, stream>>>(adj, nbr, deg);
    pad_params<<<128, 256, 0, stream>>>(Wout, aout, Wpad, apad);
    gemm1<<<dim3(N_NODES / 64, NHEADS), 256, 0, stream>>>(x, Ws, Wh1);
    attn_coef1<<<N_NODES, 256, 0, stream>>>(Wh1, a_heads, fs1t, fd1t);
    attn_agg1<<<N_NODES / 4, 256, 0, stream>>>(nbr, deg, Wh1, fs1t, fd1t, hcat);
    gemm2<<<N_NODES / 64, 256, 0, stream>>>(hcat, Wpad, Wh2);
    attn_coef2<<<N_NODES / 4, 256, 0, stream>>>(Wh2, apad, fs2, fd2);
    attn_agg2<<<N_NODES / 4, 256, 0, stream>>>(nbr, deg, Wh2, fs2, fd2, out);
}

// Round 6
// 497.531 us; speedup vs baseline: 1.0235x; 1.0015x over previous
//
#include <hip/hip_runtime.h>
#include <math.h>

#define N_NODES 8192
#define NFEAT 256
#define NHID 64
#define NHEADS 4
#define NCLASS 121
#define NCPAD 128
#define CAP 256
#define LRALPHA 0.2f

typedef float f32x4 __attribute__((ext_vector_type(4)));
typedef _Float16 f16;
typedef _Float16 f16x4 __attribute__((ext_vector_type(4)));

__device__ __forceinline__ float lrelu(float x) { return x > 0.f ? x : LRALPHA * x; }
__device__ __forceinline__ f32x4 splat4(float v) { f32x4 r = {v, v, v, v}; return r; }

// ---------------------------------------------------------------------------
// K1: build per-row neighbor lists from dense adjacency (one block per row).
// ---------------------------------------------------------------------------
__global__ __launch_bounds__(256) void build_csr(const float* __restrict__ adj,
                                                 int* __restrict__ nbr,
                                                 int* __restrict__ deg) {
    int row = blockIdx.x;
    __shared__ int cnt;
    if (threadIdx.x == 0) cnt = 0;
    __syncthreads();
    const f32x4* arow = (const f32x4*)(adj + (size_t)row * N_NODES);
    for (int j4 = threadIdx.x; j4 < N_NODES / 4; j4 += 256) {
        f32x4 v = __builtin_nontemporal_load(&arow[j4]);
        if (v.x > 0.f) { int s = atomicAdd(&cnt, 1); if (s < CAP) nbr[row * CAP + s] = j4 * 4 + 0; }
        if (v.y > 0.f) { int s = atomicAdd(&cnt, 1); if (s < CAP) nbr[row * CAP + s] = j4 * 4 + 1; }
        if (v.z > 0.f) { int s = atomicAdd(&cnt, 1); if (s < CAP) nbr[row * CAP + s] = j4 * 4 + 2; }
        if (v.w > 0.f) { int s = atomicAdd(&cnt, 1); if (s < CAP) nbr[row * CAP + s] = j4 * 4 + 3; }
    }
    __syncthreads();
    if (threadIdx.x == 0) deg[row] = cnt < CAP ? cnt : CAP;
}

// ---------------------------------------------------------------------------
// K2: pad W_out [256,121] -> [256,128] (zeros) and a_out [242] -> [256].
// ---------------------------------------------------------------------------
__global__ __launch_bounds__(256) void pad_params(const float* __restrict__ Wout,
                                                  const float* __restrict__ aout,
                                                  float* __restrict__ Wpad,
                                                  float* __restrict__ apad) {
    int idx = blockIdx.x * 256 + threadIdx.x;
    if (idx < 256 * NCPAD) {
        int k = idx >> 7, c = idx & 127;
        Wpad[idx] = (c < NCLASS) ? Wout[k * NCLASS + c] : 0.f;
    }
    if (idx < 256) {
        int c = idx & 127;
        float v = 0.f;
        if (c < NCLASS) v = (idx < 128) ? aout[c] : aout[NCLASS + c];
        apad[idx] = v;
    }
}

// ---------------------------------------------------------------------------
// K3: layer-1 GEMM. Output INTERLEAVED Wh1h[i][h*64+d] in FP16 (512 B rows):
// halves the aggregation's gather bytes (the measured bottleneck).
// ---------------------------------------------------------------------------
__global__ __launch_bounds__(256) void gemm1(const float* __restrict__ x,
                                             const float* __restrict__ Ws,
                                             f16* __restrict__ Wh1h) {
    int h = blockIdx.y;
    int r0 = blockIdx.x * 64;
    __shared__ float xs[64][260];
    for (int t = threadIdx.x; t < 64 * 64; t += 256) {
        int r = t >> 6, c4 = t & 63;
        *(float4*)&xs[r][c4 * 4] = *(const float4*)(x + (size_t)(r0 + r) * NFEAT + c4 * 4);
    }
    __syncthreads();
    int d = threadIdx.x & 63;
    int rb = (threadIdx.x >> 6) * 16;
    const float* W = Ws + (size_t)h * NFEAT * NHID + d;  // W[k][d]
    float acc[16] = {};
    for (int k4 = 0; k4 < NFEAT; k4 += 4) {
        float b0 = W[(k4 + 0) * NHID];
        float b1 = W[(k4 + 1) * NHID];
        float b2 = W[(k4 + 2) * NHID];
        float b3 = W[(k4 + 3) * NHID];
#pragma unroll
        for (int r = 0; r < 16; r++) {
            float4 a = *(const float4*)&xs[rb + r][k4];
            acc[r] += a.x * b0 + a.y * b1 + a.z * b2 + a.w * b3;
        }
    }
#pragma unroll
    for (int r = 0; r < 16; r++)
        Wh1h[(size_t)(r0 + rb + r) * (NHEADS * NHID) + h * NHID + d] = (f16)acc[r];
}

// ---------------------------------------------------------------------------
// K4: layer-1 attention coefficients from the fp16 Wh1h (score error ~1e-3,
// negligible vs the gather-value quantization). Outputs node-major float4.
// ---------------------------------------------------------------------------
__global__ __launch_bounds__(256) void attn_coef1(const f16* __restrict__ Wh1h,
                                                  const float* __restrict__ a_heads,
                                                  float* __restrict__ fs1t,
                                                  float* __restrict__ fd1t) {
    int i = blockIdx.x;
    int h = threadIdx.x >> 6, lane = threadIdx.x & 63;
    float wh = (float)Wh1h[(size_t)i * (NHEADS * NHID) + h * NHID + lane];
    float s = wh * a_heads[h * 2 * NHID + lane];
    float dd = wh * a_heads[h * 2 * NHID + NHID + lane];
#pragma unroll
    for (int o = 32; o > 0; o >>= 1) { s += __shfl_down(s, o); dd += __shfl_down(dd, o); }
    if (lane == 0) { fs1t[i * 4 + h] = s; fd1t[i * 4 + h] = dd; }
}

// ---------------------------------------------------------------------------
// K5: layer-1 sparse softmax (4 heads packed) + aggregate + ELU.
// ONE WAVE PER NODE; per edge one global_load_dwordx2 fetches the 512 B fp16
// row Wh1h[j][0:256] (lane l -> head l>>4, dims 4l..4l+3). FP32 accumulate.
// ---------------------------------------------------------------------------
__global__ __launch_bounds__(256) void attn_agg1(const int* __restrict__ nbr,
                                                 const int* __restrict__ deg,
                                                 const f16* __restrict__ Wh1h,
                                                 const float* __restrict__ fs1t,
                                                 const float* __restrict__ fd1t,
                                                 float* __restrict__ hcat) {
    int w = threadIdx.x >> 6, lane = threadIdx.x & 63;
    int i = blockIdx.x * 4 + w;
    __shared__ int nbrs[4][CAP];
    __shared__ float pbuf[4][CAP][4];   // per-edge per-head softmax numerators
    int dg = deg[i];
    for (int t = lane; t < dg; t += 64)
        nbrs[w][t] = nbr[i * CAP + t];
    f32x4 fsi = *(const f32x4*)(fs1t + (size_t)i * 4);
    f32x4 e[4];
    f32x4 m4 = splat4(-3.4e38f);
#pragma unroll
    for (int k = 0; k < 4; k++) {
        int t = lane + (k << 6);
        if (t < dg) {
            int j = nbrs[w][t];                         // own lane's writes
            f32x4 fdj = *(const f32x4*)(fd1t + (size_t)j * 4);
            f32x4 ev;
            ev.x = lrelu(fsi.x + fdj.x);
            ev.y = lrelu(fsi.y + fdj.y);
            ev.z = lrelu(fsi.z + fdj.z);
            ev.w = lrelu(fsi.w + fdj.w);
            e[k] = ev;
            m4.x = fmaxf(m4.x, ev.x); m4.y = fmaxf(m4.y, ev.y);
            m4.z = fmaxf(m4.z, ev.z); m4.w = fmaxf(m4.w, ev.w);
        }
    }
#pragma unroll
    for (int o = 32; o > 0; o >>= 1) {
        m4.x = fmaxf(m4.x, __shfl_xor(m4.x, o));
        m4.y = fmaxf(m4.y, __shfl_xor(m4.y, o));
        m4.z = fmaxf(m4.z, __shfl_xor(m4.z, o));
        m4.w = fmaxf(m4.w, __shfl_xor(m4.w, o));
    }
    f32x4 s4 = splat4(0.f);
#pragma unroll
    for (int k = 0; k < 4; k++) {
        int t = lane + (k << 6);
        if (t < dg) {
            f32x4 p;
            p.x = __expf(e[k].x - m4.x);
            p.y = __expf(e[k].y - m4.y);
            p.z = __expf(e[k].z - m4.z);
            p.w = __expf(e[k].w - m4.w);
            *(f32x4*)&pbuf[w][t][0] = p;
            s4 += p;
        }
    }
#pragma unroll
    for (int o = 32; o > 0; o >>= 1) {
        s4.x += __shfl_xor(s4.x, o);
        s4.y += __shfl_xor(s4.y, o);
        s4.z += __shfl_xor(s4.z, o);
        s4.w += __shfl_xor(s4.w, o);
    }
    __syncthreads();  // nbrs + pbuf cross-lane visibility
    int hl = lane >> 4;
    const f16* wrow = Wh1h + 4 * lane;
    f32x4 acc = splat4(0.f);
#pragma unroll 8
    for (int t = 0; t < dg; t++) {
        int j = nbrs[w][t];
        float p = pbuf[w][t][hl];
        f16x4 wv = *(const f16x4*)(wrow + (size_t)j * (NHEADS * NHID));
        acc += __builtin_convertvector(wv, f32x4) * splat4(p);
    }
    float sh = hl == 0 ? s4.x : hl == 1 ? s4.y : hl == 2 ? s4.z : s4.w;
    acc.x /= sh; acc.y /= sh; acc.z /= sh; acc.w /= sh;
    acc.x = acc.x > 0.f ? acc.x : expm1f(acc.x);
    acc.y = acc.y > 0.f ? acc.y : expm1f(acc.y);
    acc.z = acc.z > 0.f ? acc.z : expm1f(acc.z);
    acc.w = acc.w > 0.f ? acc.w : expm1f(acc.w);
    *(f32x4*)(hcat + (size_t)i * (NHEADS * NHID) + 4 * lane) = acc;
}

// ---------------------------------------------------------------------------
// K6: layer-2 GEMM. Output Wh2h[i][128] in FP16 (256 B rows) for the gather.
// ---------------------------------------------------------------------------
__global__ __launch_bounds__(256) void gemm2(const float* __restrict__ hcat,
                                             const float* __restrict__ Wpad,
                                             f16* __restrict__ Wh2h) {
    int r0 = blockIdx.x * 64;
    __shared__ float xs[64][260];
    for (int t = threadIdx.x; t < 64 * 64; t += 256) {
        int r = t >> 6, c4 = t & 63;
        *(float4*)&xs[r][c4 * 4] = *(const float4*)(hcat + (size_t)(r0 + r) * 256 + c4 * 4);
    }
    __syncthreads();
    int c0 = (threadIdx.x & 63) * 2;
    int rb = (threadIdx.x >> 6) * 16;
    float acc0[16] = {}, acc1[16] = {};
    for (int k4 = 0; k4 < 256; k4 += 4) {
        float2 b0 = *(const float2*)&Wpad[(k4 + 0) * NCPAD + c0];
        float2 b1 = *(const float2*)&Wpad[(k4 + 1) * NCPAD + c0];
        float2 b2 = *(const float2*)&Wpad[(k4 + 2) * NCPAD + c0];
        float2 b3 = *(const float2*)&Wpad[(k4 + 3) * NCPAD + c0];
#pragma unroll
        for (int r = 0; r < 16; r++) {
            float4 a = *(const float4*)&xs[rb + r][k4];
            acc0[r] += a.x * b0.x + a.y * b1.x + a.z * b2.x + a.w * b3.x;
            acc1[r] += a.x * b0.y + a.y * b1.y + a.z * b2.y + a.w * b3.y;
        }
    }
#pragma unroll
    for (int r = 0; r < 16; r++) {
        f16 v0 = (f16)acc0[r], v1 = (f16)acc1[r];
        f16* p = &Wh2h[(size_t)(r0 + rb + r) * NCPAD + c0];
        p[0] = v0; p[1] = v1;
    }
}

// ---------------------------------------------------------------------------
// K7: layer-2 attention coefficients from fp16 Wh2h.
// ---------------------------------------------------------------------------
__global__ __launch_bounds__(256) void attn_coef2(const f16* __restrict__ Wh2h,
                                                  const float* __restrict__ apad,
                                                  float* __restrict__ fs2,
                                                  float* __restrict__ fd2) {
    int i = blockIdx.x * 4 + (threadIdx.x >> 6);
    int lane = threadIdx.x & 63;
    float w0 = (float)Wh2h[(size_t)i * NCPAD + lane];
    float w1 = (float)Wh2h[(size_t)i * NCPAD + 64 + lane];
    float s = w0 * apad[lane] + w1 * apad[64 + lane];
    float dd = w0 * apad[128 + lane] + w1 * apad[192 + lane];
#pragma unroll
    for (int o = 32; o > 0; o >>= 1) { s += __shfl_down(s, o); dd += __shfl_down(dd, o); }
    if (lane == 0) { fs2[i] = s; fd2[i] = dd; }
}

// ---------------------------------------------------------------------------
// K8: layer-2 sparse softmax + aggregate. ONE WAVE PER NODE; 2 edges/iter
// (lane half eg takes edge t+eg, f16x4 over 128 cols), halves combined by
// shfl_xor(32).
// ---------------------------------------------------------------------------
__global__ __launch_bounds__(256) void attn_agg2(const int* __restrict__ nbr,
                                                 const int* __restrict__ deg,
                                                 const f16* __restrict__ Wh2h,
                                                 const float* __restrict__ fs2,
                                                 const float* __restrict__ fd2,
                                                 float* __restrict__ out) {
    int w = threadIdx.x >> 6, lane = threadIdx.x & 63;
    int i = blockIdx.x * 4 + w;
    __shared__ int nbrs[4][CAP];
    __shared__ float pbuf[4][CAP];
    int dg = deg[i];
    for (int t = lane; t < dg; t += 64)
        nbrs[w][t] = nbr[i * CAP + t];
    float fsi = fs2[i];
    float e[4];
    float m = -3.4e38f;
#pragma unroll
    for (int k = 0; k < 4; k++) {
        int t = lane + (k << 6);
        if (t < dg) {
            float ev = lrelu(fsi + fd2[nbrs[w][t]]);
            e[k] = ev;
            m = fmaxf(m, ev);
        }
    }
#pragma unroll
    for (int o = 32; o > 0; o >>= 1) m = fmaxf(m, __shfl_xor(m, o));
    float s = 0.f;
#pragma unroll
    for (int k = 0; k < 4; k++) {
        int t = lane + (k << 6);
        if (t < dg) {
            float p = __expf(e[k] - m);
            pbuf[w][t] = p;
            s += p;
        }
    }
#pragma unroll
    for (int o = 32; o > 0; o >>= 1) s += __shfl_xor(s, o);
    __syncthreads();  // nbrs + pbuf cross-lane visibility
    int eg = lane >> 5, c = lane & 31;
    const f16* wrow = Wh2h + 4 * c;
    f32x4 acc = splat4(0.f);
#pragma unroll 4
    for (int tt = 0; tt < dg; tt += 2) {
        int t = tt + eg;
        int tc = t < dg ? t : 0;         // dg >= 1 (self-loop)
        float p = t < dg ? pbuf[w][tc] : 0.f;
        int j = nbrs[w][tc];
        f16x4 wv = *(const f16x4*)(wrow + (size_t)j * NCPAD);
        acc += __builtin_convertvector(wv, f32x4) * splat4(p);
    }
    acc.x += __shfl_xor(acc.x, 32);
    acc.y += __shfl_xor(acc.y, 32);
    acc.z += __shfl_xor(acc.z, 32);
    acc.w += __shfl_xor(acc.w, 32);
    if (eg == 0) {
        int c4 = c * 4;
#pragma unroll
        for (int q = 0; q < 4; q++)
            if (c4 + q < NCLASS) out[(size_t)i * NCLASS + c4 + q] = acc[q] / s;
    }
}

// ---------------------------------------------------------------------------

extern "C" void kernel_launch(void* const* d_in, const int* in_sizes, int n_in,
                              void* d_out, int out_size, void* d_ws, size_t ws_size,
                              hipStream_t stream) {
    const float* x       = (const float*)d_in[0];  // [8192,256]
    const float* adj     = (const float*)d_in[1];  // [8192,8192]
    const float* Ws      = (const float*)d_in[2];  // [4,256,64]
    const float* a_heads = (const float*)d_in[3];  // [4,128]
    const float* Wout    = (const float*)d_in[4];  // [256,121]
    const float* aout    = (const float*)d_in[5];  // [242]
    float* out = (float*)d_out;                    // [8192,121]

    char* ws = (char*)d_ws;
    size_t off = 0;
    auto alloc = [&](size_t bytes) { void* p = ws + off; off = (off + bytes + 255) & ~(size_t)255; return p; };
    int*   nbr  = (int*)  alloc((size_t)N_NODES * CAP * 4);            // 8 MB
    int*   deg  = (int*)  alloc((size_t)N_NODES * 4);                  // 32 KB
    f16*   Wh1h = (f16*)  alloc((size_t)N_NODES * NHEADS * NHID * 2);  // 4 MB fp16
    float* fs1t = (float*)alloc((size_t)N_NODES * 4 * 4);              // 128 KB
    float* fd1t = (float*)alloc((size_t)N_NODES * 4 * 4);              // 128 KB
    float* hcat = (float*)alloc((size_t)N_NODES * NHEADS * NHID * 4);  // 8 MB fp32
    f16*   Wh2h = (f16*)  alloc((size_t)N_NODES * NCPAD * 2);          // 2 MB fp16
    float* fs2  = (float*)alloc((size_t)N_NODES * 4);
    float* fd2  = (float*)alloc((size_t)N_NODES * 4);
    float* Wpad = (float*)alloc((size_t)256 * NCPAD * 4);
    float* apad = (float*)alloc((size_t)256 * 4);

    build_csr<<<N_NODES, 256, 0, stream>>>(adj, nbr, deg);
    pad_params<<<128, 256, 0, stream>>>(Wout, aout, Wpad, apad);
    gemm1<<<dim3(N_NODES / 64, NHEADS), 256, 0, stream>>>(x, Ws, Wh1h);
    attn_coef1<<<N_NODES, 256, 0, stream>>>(Wh1h, a_heads, fs1t, fd1t);
    attn_agg1<<<N_NODES / 4, 256, 0, stream>>>(nbr, deg, Wh1h, fs1t, fd1t, hcat);
    gemm2<<<N_NODES / 64, 256, 0, stream>>>(hcat, Wpad, Wh2h);
    attn_coef2<<<N_NODES / 4, 256, 0, stream>>>(Wh2h, apad, fs2, fd2);
    attn_agg2<<<N_NODES / 4, 256, 0, stream>>>(nbr, deg, Wh2h, fs2, fd2, out);
}